// Round 3
// baseline (449.603 us; speedup 1.0000x reference)
//
#include <hip/hip_runtime.h>
#include <math.h>

// HairBundle SDE drift+diffusion, fp32 elementwise, B=8,000,000 rows of 5 vars.
// out = drift[B,5] flat ++ diffusion[B,5] flat.
//
// R5: no-LDS register kernel. Evidence so far: R2 (LDS transpose, NT, 411.2us)
// vs R3/R4 (async staging + pre-barrier diff stores, 426.9/421.4us) shows the
// LDS/staging structure is not the lever, and diff-stores-before-barrier HURT
// (vmcnt drains stores at the barrier). This version removes LDS and barriers
// entirely: each thread owns 4 consecutive rows = 5 consecutive float4s.
//  - 5x global_load_dwordx4 (plain, so L1 caches the 80B-stride line reuse)
//  - all 4 rows computed in registers (static indexing only -> no scratch)
//  - 5x float4 drift stores, 5x constant float4 diff stores (thread phase
//    20*i mod 5 == 0 -> diffusion pattern is a compile-time constant)
//  - diff stores issued LAST (post-mortem: stores share vmcnt; never put
//    them ahead of anything that waits).

typedef float f4 __attribute__((ext_vector_type(4)));

#define THREADS         128
#define ROWS_PER_THREAD 4
#define ROWS_PER_BLOCK  (THREADS * ROWS_PER_THREAD)   // 512 rows
#define F4_PER_THREAD   5                             // 20 floats = 4 rows

// One row of the hair-bundle drift. force is wave-uniform.
#define HB_ROW(xhb, xa, pm, pgs, pt, o0, o1, o2, o3, o4)                 \
    do {                                                                 \
        const float p_o  = 1.0f / (1.0f + __expf(-4.0f * ((xhb) - (xa)))); \
        const float f_gs = 0.75f * ((xhb) - (xa) - 0.5f * p_o);          \
        (o0) = -f_gs - 0.6f * (xhb) + force;                             \
        (o1) = 0.1f * (f_gs - 0.45f * (xa) - 0.35f * (1.0f - 0.9f * (pm))); \
        (o2) = 1.2f * p_o * (1.0f - (pm))  - 0.8f * (pm);                \
        (o3) = 0.7f * p_o * (1.0f - (pgs)) - 0.5f * (pgs);               \
        (o4) = 0.3f * p_o * (1.0f - (pt))  - 0.4f * (pt);                \
    } while (0)

__global__ __launch_bounds__(THREADS) void hb_sde_kernel(
    const float* __restrict__ t,
    const float* __restrict__ x,
    float* __restrict__ drift,
    float* __restrict__ diff)
{
    const int i = threadIdx.x;
    // this thread's first float4 (thread-contiguous: 5 f4 per thread)
    const long long tf4 =
        (long long)blockIdx.x * (ROWS_PER_BLOCK * 5 / 4) + (long long)i * F4_PER_THREAD;

    // ---- load 4 rows = 5 float4 into registers (plain cached loads) ----
    const f4* __restrict__ xv = (const f4*)x + tf4;
    const f4 a0 = xv[0];
    const f4 a1 = xv[1];
    const f4 a2 = xv[2];
    const f4 a3 = xv[3];
    const f4 a4 = xv[4];

    // wave-uniform sinusoidal drive (scalar path, overlaps the loads)
    const float force = 0.5f * sinf(6.283185307179586f * t[0]);

    // ---- compute 4 rows fully in registers (static element indexing) ----
    f4 d0, d1, d2, d3, d4;
    //        x_hb   x_a    p_m    p_gs   p_t     dx_hb  dx_a   dp_m   dp_gs  dp_t
    HB_ROW(a0.x,  a0.y,  a0.z,  a0.w,  a1.x,   d0.x,  d0.y,  d0.z,  d0.w,  d1.x);
    HB_ROW(a1.y,  a1.z,  a1.w,  a2.x,  a2.y,   d1.y,  d1.z,  d1.w,  d2.x,  d2.y);
    HB_ROW(a2.z,  a2.w,  a3.x,  a3.y,  a3.z,   d2.z,  d2.w,  d3.x,  d3.y,  d3.z);
    HB_ROW(a3.w,  a4.x,  a4.y,  a4.z,  a4.w,   d3.w,  d4.x,  d4.y,  d4.z,  d4.w);

    // ---- drift stores ----
    f4* __restrict__ dv = (f4*)drift + tf4;
    dv[0] = d0;
    dv[1] = d1;
    dv[2] = d2;
    dv[3] = d3;
    dv[4] = d4;

    // ---- diffusion: value at float p is c[p%5], c={0.05,0.02,0,0,0}.
    // Thread's first float is 20*i -> phase 0 always: pattern is constant.
    f4* __restrict__ gv = (f4*)diff + tf4;
    gv[0] = (f4){0.05f, 0.02f, 0.0f,  0.0f };   // j 0..3
    gv[1] = (f4){0.0f,  0.05f, 0.02f, 0.0f };   // j 4..7
    gv[2] = (f4){0.0f,  0.0f,  0.05f, 0.02f};   // j 8..11
    gv[3] = (f4){0.0f,  0.0f,  0.0f,  0.05f};   // j 12..15
    gv[4] = (f4){0.02f, 0.0f,  0.0f,  0.0f };   // j 16..19
}

extern "C" void kernel_launch(void* const* d_in, const int* in_sizes, int n_in,
                              void* d_out, int out_size, void* d_ws, size_t ws_size,
                              hipStream_t stream) {
    const float* t = (const float*)d_in[0];
    const float* x = (const float*)d_in[1];
    float* out = (float*)d_out;

    const long long batch = (long long)in_sizes[1] / 5;   // 8,000,000
    float* drift = out;
    float* diff  = out + batch * 5;

    const int nblocks = (int)(batch / ROWS_PER_BLOCK);    // 15625, exact
    hb_sde_kernel<<<nblocks, THREADS, 0, stream>>>(t, x, drift, diff);
}

// Round 4
// 411.772 us; speedup vs baseline: 1.0919x; 1.0919x over previous
//
#include <hip/hip_runtime.h>
#include <math.h>

// HairBundle SDE drift+diffusion, fp32 elementwise, B=8,000,000 rows of 5 vars.
// out = drift[B,5] flat ++ diffusion[B,5] flat.
//
// R6 = revert to R2 (best measured: 410.9 / 411.2 us across two sessions).
// Session ladder: R2 411.2 | R3 async-LDS+diff-early 426.9 | R4 plain stores
// 421.4 | R5 register-only 449.6. Four structures all >= R2 -> the kernel
// component (~80 us for 480 MB at the in-capture-proven 6.3-6.4 TB/s) is at
// the BW floor; the rest of the timed region is the harness's 1.28 GB poison
// fill (~200 us, measured every round) + reset dispatch train (~130 us),
// neither addressable from kernel_launch.
//
// Structure: LDS-transpose staging for per-instruction coalescing; NT
// loads/stores; diffusion (constant pattern) stored last.

typedef float f4 __attribute__((ext_vector_type(4)));

#define THREADS        128
#define ROWS_PER_BLOCK 512                        // 512 rows * 5 fl = 640 float4
#define F4_PER_BLOCK   (ROWS_PER_BLOCK * 5 / 4)   // 640
#define F4_PER_THREAD  (F4_PER_BLOCK / THREADS)   // 5
#define ROWS_PER_THREAD (ROWS_PER_BLOCK / THREADS) // 4

__global__ __launch_bounds__(THREADS) void hb_sde_kernel(
    const float* __restrict__ t,
    const float* __restrict__ x,
    float* __restrict__ drift,
    float* __restrict__ diff)
{
    __shared__ float lds[ROWS_PER_BLOCK * 5];     // 10 KB

    const int i = threadIdx.x;
    const long long f4base = (long long)blockIdx.x * F4_PER_BLOCK;

    // wave-uniform sinusoidal drive
    const float force = 0.5f * sinf(6.283185307179586f * t[0]);

    // ---- coalesced global -> LDS (lane i handles float4 i, i+128, ...) ----
    const f4* __restrict__ xv = (const f4*)x + f4base;
    f4* lv = (f4*)lds;
#pragma unroll
    for (int k = 0; k < F4_PER_THREAD; ++k)
        lv[i + k * THREADS] = __builtin_nontemporal_load(&xv[i + k * THREADS]);
    __syncthreads();

    // ---- per-thread rows from LDS; overwrite own row with drift ----
#pragma unroll
    for (int r = 0; r < ROWS_PER_THREAD; ++r) {
        const int o = (i * ROWS_PER_THREAD + r) * 5;
        const float x_hb = lds[o + 0];
        const float x_a  = lds[o + 1];
        const float p_m  = lds[o + 2];
        const float p_gs = lds[o + 3];
        const float p_t  = lds[o + 4];

        // p_o = sigmoid((x_hb - x_a)/DELTA), DELTA = 0.25
        const float p_o  = 1.0f / (1.0f + __expf(-4.0f * (x_hb - x_a)));
        // f_gs = K_GS*(x_hb - x_a - D_GATE*p_o)
        const float f_gs = 0.75f * (x_hb - x_a - 0.5f * p_o);

        lds[o + 0] = -f_gs - 0.6f * x_hb + force;
        lds[o + 1] = 0.1f * (f_gs - 0.45f * x_a - 0.35f * (1.0f - 0.9f * p_m));
        lds[o + 2] = 1.2f * p_o * (1.0f - p_m)  - 0.8f * p_m;
        lds[o + 3] = 0.7f * p_o * (1.0f - p_gs) - 0.5f * p_gs;
        lds[o + 4] = 0.3f * p_o * (1.0f - p_t)  - 0.4f * p_t;
    }
    __syncthreads();

    // ---- coalesced LDS -> global drift ----
    f4* __restrict__ dv = (f4*)drift + f4base;
#pragma unroll
    for (int k = 0; k < F4_PER_THREAD; ++k)
        __builtin_nontemporal_store(lv[i + k * THREADS], &dv[i + k * THREADS]);

    // ---- diffusion: constant pattern, direct coalesced stores ----
    // float4 index g covers floats 4g..4g+3; value at float p is c[p%5],
    // c = {0.05, 0.02, 0, 0, 0}. F4_PER_BLOCK=640 is divisible by 5, so
    // g % 5 == (i + k*THREADS) % 5 (block-independent).
    f4* __restrict__ gv = (f4*)diff + f4base;
#pragma unroll
    for (int k = 0; k < F4_PER_THREAD; ++k) {
        const int m = (i + k * THREADS) % 5;
        f4 v;
        v.x = (m == 0) ? 0.05f : ((m == 4) ? 0.02f : 0.0f);
        v.y = (m == 0) ? 0.02f : ((m == 1) ? 0.05f : 0.0f);
        v.z = (m == 1) ? 0.02f : ((m == 2) ? 0.05f : 0.0f);
        v.w = (m == 2) ? 0.02f : ((m == 3) ? 0.05f : 0.0f);
        __builtin_nontemporal_store(v, &gv[i + k * THREADS]);
    }
}

extern "C" void kernel_launch(void* const* d_in, const int* in_sizes, int n_in,
                              void* d_out, int out_size, void* d_ws, size_t ws_size,
                              hipStream_t stream) {
    const float* t = (const float*)d_in[0];
    const float* x = (const float*)d_in[1];
    float* out = (float*)d_out;

    const long long batch = (long long)in_sizes[1] / 5;   // 8,000,000
    float* drift = out;
    float* diff  = out + batch * 5;

    const int nblocks = (int)(batch / ROWS_PER_BLOCK);    // 15625, exact
    hb_sde_kernel<<<nblocks, THREADS, 0, stream>>>(t, x, drift, diff);
}